// Round 1
// baseline (462.564 us; speedup 1.0000x reference)
//
#include <hip/hip_runtime.h>

typedef unsigned short u16;
typedef short bfrag __attribute__((ext_vector_type(8)));   // 8 x bf16 (4 VGPR)
typedef float f32x4 __attribute__((ext_vector_type(4)));
typedef const __attribute__((address_space(1))) unsigned int* gp1_t;
typedef __attribute__((address_space(3))) unsigned int* lp3_t;

#define B_ 8192
#define H_ 1024
#define P_ 2048

__device__ __forceinline__ u16 f2bf(float f) {
  unsigned u = __builtin_bit_cast(unsigned, f);
  u += 0x7fffu + ((u >> 16) & 1u);
  return (u16)(u >> 16);
}
__device__ __forceinline__ float bf2f(u16 s) {
  return __builtin_bit_cast(float, (unsigned)s << 16);
}
__device__ __forceinline__ float sigm(float v) { return 1.f / (1.f + __expf(-v)); }

// ---------------- elementwise / reduction kernels ----------------

__global__ void k_activity(const float* __restrict__ hidden, float* __restrict__ act) {
  int t = threadIdx.x;
  const float* p = hidden + (size_t)blockIdx.x * 128 * H_;
  float s0 = 0, s1 = 0, s2 = 0, s3 = 0;
  for (int r = 0; r < 128; ++r) {
    const float* q = p + (size_t)r * H_;
    s0 += fabsf(q[t]); s1 += fabsf(q[t + 256]);
    s2 += fabsf(q[t + 512]); s3 += fabsf(q[t + 768]);
  }
  atomicAdd(&act[t], s0); atomicAdd(&act[t + 256], s1);
  atomicAdd(&act[t + 512], s2); atomicAdd(&act[t + 768], s3);
}

__global__ void k_cs(const float* __restrict__ act, const float* __restrict__ strength,
                     const float* __restrict__ decay, const float* __restrict__ hist,
                     float* __restrict__ cs) {
  int h = blockIdx.x * 256 + threadIdx.x;
  float ch = hist[h] * decay[0] + act[h] * (1.f / (float)B_);
  cs[h] = strength[h] * sigm(ch);
}

__global__ void k_f32_to_bf16(const float* __restrict__ s, u16* __restrict__ d, int n4) {
  int i = blockIdx.x * blockDim.x + threadIdx.x;
  if (i < n4) {
    float4 v = ((const float4*)s)[i];
    ushort4 o;
    o.x = f2bf(v.x); o.y = f2bf(v.y); o.z = f2bf(v.z); o.w = f2bf(v.w);
    ((ushort4*)d)[i] = o;
  }
}

// x (f32 [B,1024]) -> combined[:, 0:1024] bf16 with row stride 2048
__global__ void k_pack_x(const float* __restrict__ x, u16* __restrict__ comb) {
  int i = blockIdx.x * blockDim.x + threadIdx.x;   // over B*H/4
  int row = i >> 8;
  int c4 = i & 255;
  float4 v = ((const float4*)x)[i];
  ushort4 o;
  o.x = f2bf(v.x); o.y = f2bf(v.y); o.z = f2bf(v.z); o.w = f2bf(v.w);
  *(ushort4*)&comb[(size_t)row * 2048 + c4 * 4] = o;
}

// combined[:,1024+c] = bf16(reset * ha)   (ha currently stored there as bf16)
__global__ void k_creset(const float* __restrict__ reset, u16* __restrict__ comb) {
  int i = blockIdx.x * blockDim.x + threadIdx.x;   // over B*H/4
  int row = i >> 8;
  int c4 = i & 255;
  float4 r = ((const float4*)reset)[i];
  u16* p = &comb[(size_t)row * 2048 + 1024 + c4 * 4];
  ushort4 h = *(ushort4*)p;
  ushort4 o;
  o.x = f2bf(r.x * bf2f(h.x)); o.y = f2bf(r.y * bf2f(h.y));
  o.z = f2bf(r.z * bf2f(h.z)); o.w = f2bf(r.w * bf2f(h.w));
  *(ushort4*)p = o;
}

__global__ void k_rowmean(const float* __restrict__ hn, float* __restrict__ hp) {
  int row = blockIdx.x * 4 + (threadIdx.x >> 6);
  int lane = threadIdx.x & 63;
  const float* p = hn + (size_t)row * H_;
  float s = 0.f;
#pragma unroll
  for (int c = 0; c < H_ / 64; ++c) s += p[lane + c * 64];
#pragma unroll
  for (int o = 32; o; o >>= 1) s += __shfl_down(s, o);
  if (lane == 0) hp[row] = s * (1.f / (float)H_);
}

// ---------------- GEMM: C[M,N] = A[M,K] * B[N,K]^T, bf16 in, f32 acc ----------------

struct GemmPs {
  const u16* Bm[4];
  const float* bias[4];
  const float* hidden;   // f32 [B,1024]
  const float* update;   // f32 [B,1024]
  const float* cs;       // [1024]
  float* out_f0;         // reset
  float* out_f1;         // update
  float* hn_f32;
  u16* hn_bf16;
  u16* combined;         // [B,2048] bf16
  u16* out_b[4];         // gate logits bf16 [B,2048]
};

template <int EPI>
__device__ __forceinline__ void epi(int row, int col, float v, int z, const GemmPs& e) {
  if constexpr (EPI == 1) {            // attention -> ha -> combined[:,1024+col]
    v += e.bias[0][col];
    float a = sigm(v);
    float ha = e.hidden[(size_t)row * H_ + col] * a;
    e.combined[(size_t)row * 2048 + 1024 + col] = f2bf(ha);
  } else if constexpr (EPI == 2) {     // reset / update raw f32
    v += e.bias[z][col];
    float* o = (z == 0) ? e.out_f0 : e.out_f1;
    o[(size_t)row * H_ + col] = v;
  } else if constexpr (EPI == 3) {     // new -> hidden_new
    v += e.bias[0][col];
    size_t i = (size_t)row * H_ + col;
    float u = e.update[i];
    float hn = (1.f - u) * e.hidden[i] + u * v * e.cs[col];
    e.hn_f32[i] = hn;
    e.hn_bf16[i] = f2bf(hn);
  } else {                             // gate logits bf16
    v += e.bias[z][col];
    e.out_b[z][(size_t)row * P_ + col] = f2bf(v);
  }
}

// 128x128 tile, BK=64, 4 waves (2x2), each wave 64x64 (4x4 frags of 16x16x32).
// LDS layout XOR-swizzled: element col slot s (8 elems = 16B) stored at s^(row&7).
// Staging pre-swizzles the GLOBAL source so global_load_lds can write linearly (m173).
template <int EPI>
__global__ __launch_bounds__(256, 2) void gemm_bt(const u16* __restrict__ A, int K, GemmPs e) {
  const int z = blockIdx.z;
  const u16* __restrict__ Bm = e.Bm[z];
  __shared__ u16 As[128 * 64];
  __shared__ u16 Bs[128 * 64];
  const int lane = threadIdx.x & 63;
  const int w = threadIdx.x >> 6;
  const int wr = w >> 1, wc = w & 1;
  const int m0 = blockIdx.x * 128, n0 = blockIdx.y * 128;

  f32x4 acc[4][4] = {};

  // staging: lane l covers LDS row (w*32 + j*8 + (l>>3)), 16B slot (l&7).
  // source column pre-swizzled: slot ^ (row&7) where row&7 == (l>>3)&7.
  const int rA = lane >> 3;
  const int srcSlot = (lane & 7) ^ (rA & 7);
  const u16* pA = A + (size_t)(m0 + w * 32 + rA) * K + srcSlot * 8;
  const u16* pB = Bm + (size_t)(n0 + w * 32 + rA) * K + srcSlot * 8;

  const int g = lane >> 4;        // 0..3
  const int r15 = lane & 15;
  const int rx = lane & 7;        // row&7 for fragment reads

  for (int k0 = 0; k0 < K; k0 += 64) {
#pragma unroll
    for (int j = 0; j < 4; ++j) {
      __builtin_amdgcn_global_load_lds((gp1_t)(pA + (size_t)j * 8 * K + k0),
                                       (lp3_t)&As[(w * 32 + j * 8) * 64], 16, 0, 0);
      __builtin_amdgcn_global_load_lds((gp1_t)(pB + (size_t)j * 8 * K + k0),
                                       (lp3_t)&Bs[(w * 32 + j * 8) * 64], 16, 0, 0);
    }
    asm volatile("s_waitcnt vmcnt(0)" ::: "memory");
    __syncthreads();
#pragma unroll
    for (int kk = 0; kk < 64; kk += 32) {
      const int slot = g + (kk >> 3);       // kk=0 -> g, kk=32 -> 4+g
      const int cswz = ((slot ^ rx) << 3);  // swizzled element col
      bfrag af[4], bq[4];
#pragma unroll
      for (int i = 0; i < 4; ++i) {
        af[i] = *(const bfrag*)&As[(wr * 64 + i * 16 + r15) * 64 + cswz];
        bq[i] = *(const bfrag*)&Bs[(wc * 64 + i * 16 + r15) * 64 + cswz];
      }
#pragma unroll
      for (int mi = 0; mi < 4; ++mi)
#pragma unroll
        for (int ni = 0; ni < 4; ++ni)
          acc[mi][ni] = __builtin_amdgcn_mfma_f32_16x16x32_bf16(af[mi], bq[ni], acc[mi][ni], 0, 0, 0);
    }
    __syncthreads();
  }

  // C/D layout: col = lane&15, row = (lane>>4)*4 + reg   [m89-verified]
#pragma unroll
  for (int mi = 0; mi < 4; ++mi)
#pragma unroll
    for (int ni = 0; ni < 4; ++ni)
#pragma unroll
      for (int r = 0; r < 4; ++r)
        epi<EPI>(m0 + wr * 64 + mi * 16 + g * 4 + r,
                 n0 + wc * 64 + ni * 16 + r15, acc[mi][ni][r], z, e);
}

// ---------------- final: softmax(addr), sigmoids, memory_new, hidden_final ----------------

__global__ __launch_bounds__(256) void k_final(
    const u16* __restrict__ aL, const u16* __restrict__ rL,
    const u16* __restrict__ wL, const u16* __restrict__ fL,
    const float* __restrict__ pm, const float* __restrict__ hn,
    const float* __restrict__ hp, float* __restrict__ outH, float* __restrict__ outM) {
  __shared__ float sl[P_];
  __shared__ float red[8];
  const int row = blockIdx.x, t = threadIdx.x;
  const size_t base = (size_t)row * P_;

  float lm = -3.4e38f;
  for (int p = t; p < P_; p += 256) {
    float v = bf2f(aL[base + p]);
    sl[p] = v;
    lm = fmaxf(lm, v);
  }
#pragma unroll
  for (int o = 32; o; o >>= 1) lm = fmaxf(lm, __shfl_down(lm, o));
  if ((t & 63) == 0) red[t >> 6] = lm;
  __syncthreads();
  const float bmax = fmaxf(fmaxf(red[0], red[1]), fmaxf(red[2], red[3]));

  float ls = 0.f;
  for (int p = t; p < P_; p += 256) {
    float ev = __expf(sl[p] - bmax);
    sl[p] = ev;
    ls += ev;
  }
#pragma unroll
  for (int o = 32; o; o >>= 1) ls += __shfl_down(ls, o);
  if ((t & 63) == 0) red[4 + (t >> 6)] = ls;
  __syncthreads();
  const float inv = 1.f / (red[4] + red[5] + red[6] + red[7]);
  const float hpv = hp[row];

  float rs = 0.f;
  for (int p = t; p < P_; p += 256) {
    float a = sl[p] * inv;
    float fo = sigm(bf2f(fL[base + p]));
    float wv = sigm(bf2f(wL[base + p]));
    float rd = sigm(bf2f(rL[base + p]));
    float mem = fo * pm[base + p] + wv * hpv * a;
    outM[base + p] = mem;
    rs += rd * mem;
  }
#pragma unroll
  for (int o = 32; o; o >>= 1) rs += __shfl_down(rs, o);
  __syncthreads();
  if ((t & 63) == 0) red[t >> 6] = rs;
  __syncthreads();
  const float mean = (red[0] + red[1] + red[2] + red[3]) * (1.f / (float)P_);
  const size_t hb = (size_t)row * H_;
  for (int h = t; h < H_; h += 256) outH[hb + h] = hn[hb + h] + mean;
}

// ---------------- host ----------------

extern "C" void kernel_launch(void* const* d_in, const int* in_sizes, int n_in,
                              void* d_out, int out_size, void* d_ws, size_t ws_size,
                              hipStream_t stream) {
  (void)in_sizes; (void)n_in; (void)out_size; (void)ws_size;
  const float* x       = (const float*)d_in[0];
  const float* hidden  = (const float*)d_in[1];
  const float* pm      = (const float*)d_in[2];
  const float* Wa      = (const float*)d_in[3];
  const float* ba      = (const float*)d_in[4];
  const float* Wr      = (const float*)d_in[5];
  const float* br      = (const float*)d_in[6];
  const float* Wu      = (const float*)d_in[7];
  const float* bu      = (const float*)d_in[8];
  const float* Wn      = (const float*)d_in[9];
  const float* bn      = (const float*)d_in[10];
  const float* Wread   = (const float*)d_in[11];
  const float* bread   = (const float*)d_in[12];
  const float* Wwrite  = (const float*)d_in[13];
  const float* bwrite  = (const float*)d_in[14];
  const float* Wforget = (const float*)d_in[15];
  const float* bforget = (const float*)d_in[16];
  const float* Waddr   = (const float*)d_in[17];
  const float* baddr   = (const float*)d_in[18];
  const float* cstr    = (const float*)d_in[19];
  const float* cdecay  = (const float*)d_in[20];
  const float* chist   = (const float*)d_in[21];

  char* wsp = (char*)d_ws;
  auto take = [&](size_t n) { char* p = wsp; wsp += (n + 255) & ~(size_t)255; return p; };
  float* act    = (float*)take((size_t)H_ * 4);
  float* cs     = (float*)take((size_t)H_ * 4);
  float* hp     = (float*)take((size_t)B_ * 4);
  u16* hiddenB  = (u16*)take((size_t)B_ * H_ * 2);      // later reused as hidden_new bf16
  u16* WaB      = (u16*)take((size_t)H_ * H_ * 2);
  u16* WrB      = (u16*)take((size_t)H_ * 2048 * 2);
  u16* WuB      = (u16*)take((size_t)H_ * 2048 * 2);
  u16* WnB      = (u16*)take((size_t)H_ * 2048 * 2);
  u16* WadB     = (u16*)take((size_t)P_ * H_ * 2);
  u16* WrdB     = (u16*)take((size_t)P_ * H_ * 2);
  u16* WwrB     = (u16*)take((size_t)P_ * H_ * 2);
  u16* WfgB     = (u16*)take((size_t)P_ * H_ * 2);
  u16* combined = (u16*)take((size_t)B_ * 2048 * 2);
  float* reset  = (float*)take((size_t)B_ * H_ * 4);
  float* update = (float*)take((size_t)B_ * H_ * 4);
  float* hnf    = (float*)take((size_t)B_ * H_ * 4);
  u16* gAd      = (u16*)take((size_t)B_ * P_ * 2);
  u16* gRd      = (u16*)take((size_t)B_ * P_ * 2);
  u16* gWr      = (u16*)take((size_t)B_ * P_ * 2);
  u16* gFg      = (u16*)take((size_t)B_ * P_ * 2);

  float* outH = (float*)d_out;
  float* outM = outH + (size_t)B_ * H_;

  // connection strength
  hipMemsetAsync(act, 0, (size_t)H_ * 4, stream);
  k_activity<<<dim3(64), dim3(256), 0, stream>>>(hidden, act);
  k_cs<<<dim3(4), dim3(256), 0, stream>>>(act, cstr, cdecay, chist, cs);

  // conversions
  auto conv = [&](const float* s, u16* d, size_t n) {
    k_f32_to_bf16<<<dim3((unsigned)(n / 4 / 256)), dim3(256), 0, stream>>>(s, d, (int)(n / 4));
  };
  conv(Wa, WaB, (size_t)H_ * H_);
  conv(Wr, WrB, (size_t)H_ * 2048);
  conv(Wu, WuB, (size_t)H_ * 2048);
  conv(Wn, WnB, (size_t)H_ * 2048);
  conv(Waddr, WadB, (size_t)P_ * H_);
  conv(Wread, WrdB, (size_t)P_ * H_);
  conv(Wwrite, WwrB, (size_t)P_ * H_);
  conv(Wforget, WfgB, (size_t)P_ * H_);
  conv(hidden, hiddenB, (size_t)B_ * H_);
  k_pack_x<<<dim3(8192), dim3(256), 0, stream>>>(x, combined);

  // GEMM 1: attention -> ha -> combined[:,1024:]
  {
    GemmPs e{};
    e.Bm[0] = WaB; e.bias[0] = ba; e.hidden = hidden; e.combined = combined;
    gemm_bt<1><<<dim3(64, 8, 1), dim3(256), 0, stream>>>(hiddenB, 1024, e);
  }
  // GEMM 2/3: reset, update (raw)
  {
    GemmPs e{};
    e.Bm[0] = WrB; e.Bm[1] = WuB; e.bias[0] = br; e.bias[1] = bu;
    e.out_f0 = reset; e.out_f1 = update;
    gemm_bt<2><<<dim3(64, 8, 2), dim3(256), 0, stream>>>(combined, 2048, e);
  }
  // combined[:,1024:] = bf16(reset * ha)
  k_creset<<<dim3(8192), dim3(256), 0, stream>>>(reset, combined);
  // GEMM 4: new -> hidden_new (f32 + bf16)
  {
    GemmPs e{};
    e.Bm[0] = WnB; e.bias[0] = bn; e.hidden = hidden; e.update = update; e.cs = cs;
    e.hn_f32 = hnf; e.hn_bf16 = hiddenB;
    gemm_bt<3><<<dim3(64, 8, 1), dim3(256), 0, stream>>>(combined, 2048, e);
  }
  k_rowmean<<<dim3(2048), dim3(256), 0, stream>>>(hnf, hp);
  // GEMMs 5-8: gate logits (addr, read, write, forget)
  {
    GemmPs e{};
    e.Bm[0] = WadB; e.Bm[1] = WrdB; e.Bm[2] = WwrB; e.Bm[3] = WfgB;
    e.bias[0] = baddr; e.bias[1] = bread; e.bias[2] = bwrite; e.bias[3] = bforget;
    e.out_b[0] = gAd; e.out_b[1] = gRd; e.out_b[2] = gWr; e.out_b[3] = gFg;
    gemm_bt<4><<<dim3(64, 16, 4), dim3(256), 0, stream>>>(hiddenB, 1024, e);
  }
  // final fused softmax / gates / outputs
  k_final<<<dim3(B_), dim3(256), 0, stream>>>(gAd, gRd, gWr, gFg, pm, hnf, hp, outH, outM);
}